// Round 8
// baseline (607.006 us; speedup 1.0000x reference)
//
#include <hip/hip_runtime.h>
#include <hip/hip_fp16.h>

// NNUE forward: embedding-bag (2x32 gathers of 256-dim rows) -> clipped relu
// -> 512->32->32->1 MLP.
//
// R8 = R7 with compile fix: __builtin_nontemporal_load can't take HIP's
// uint4 struct type -> load via ext_vector_type(4) unsigned.
//
// R7 design: XCD-L2-resident gather. R2/R3/R6 pinned the L2-miss path at
// ~3.6 TB/s (per-XCD fabric ceiling) with 1.7 GB misses/dispatch -> change
// data placement:
//  - table repacked into 8 contiguous 32-dim slices (2.62 MB each, L2-fits)
//  - gather kernel: slice = blockIdx&7 (block->XCD round-robin) so each XCD
//    streams its rows from ITS OWN L2; reduce-scatter over 16 row-groups;
//    clipped f16 x written to ws (nontemporal)
//  - MLP kernel: reads x coalesced, fdot2 layers as before
// Fallbacks: ws >= 21 MB -> fused R6 kernel; else f32 kernel.

constexpr int kBatch  = 131072;
constexpr int kHidden = 256;
constexpr int kBag    = 32;
constexpr int kFeat   = 40960;

constexpr int    kSlices     = 8;
constexpr int    kSliceDims  = 32;                                   // cols/slice
constexpr size_t kSliceBytes = (size_t)kFeat * kSliceDims * 2;       // 2.62 MB
constexpr size_t kEmbsBytes  = kSliceBytes * kSlices;                // 21 MB
constexpr size_t kXBytes     = (size_t)kBatch * 2 * kHidden * 2;     // 134 MB

typedef unsigned u32x4 __attribute__((ext_vector_type(4)));

__device__ __forceinline__ float clip1(float x) {
  return fminf(fmaxf(x, 0.0f), 1.0f);  // v_med3_f32
}

typedef _Float16 h2_t __attribute__((ext_vector_type(2)));

__device__ __forceinline__ unsigned pkadd(unsigned a, unsigned b) {
  const h2_t r = __builtin_bit_cast(h2_t, a) + __builtin_bit_cast(h2_t, b);
  return __builtin_bit_cast(unsigned, r);  // v_pk_add_f16
}

__device__ __forceinline__ unsigned pkclip(unsigned a) {
  unsigned r;
  const unsigned zero = 0u;            // {0.0h, 0.0h}
  const unsigned one  = 0x3C003C00u;   // {1.0h, 1.0h}
  asm("v_pk_max_f16 %0, %1, %2\n\t"
      "v_pk_min_f16 %0, %0, %3"
      : "=&v"(r)
      : "v"(a), "v"(zero), "v"(one));
  return r;
}

// v_dot2_f32_f16: c += a.x*b.x + a.y*b.y (f32 accumulate, f16 inputs)
__device__ __forceinline__ float fdot2w(unsigned a, unsigned b, float c) {
  return __builtin_amdgcn_fdot2(__builtin_bit_cast(h2_t, a),
                                __builtin_bit_cast(h2_t, b), c, false);
}

// One butterfly reduce-scatter stage; ALL indices compile-time constants.
template <int D, int HALF>
__device__ __forceinline__ void rs_stage(float (&p)[32], int lane) {
  const bool up = (lane & D) != 0;
#pragma unroll
  for (int i = 0; i < HALF; ++i) {
    const float send = up ? p[i] : p[i + HALF];
    const float recv = __shfl_xor(send, D, 64);
    p[i] = (up ? p[i + HALF] : p[i]) + recv;
  }
}

__device__ __forceinline__ float reduce32(float (&p)[32], int lane) {
  rs_stage<32, 16>(p, lane);
  rs_stage<16, 8>(p, lane);
  rs_stage<8, 4>(p, lane);
  rs_stage<4, 2>(p, lane);
  rs_stage<2, 1>(p, lane);
  return p[0] + __shfl_xor(p[0], 1, 64);
}

// ---------------------------------------------------------------------------
// Table repack: f32 [kFeat][256] -> f16 sliced [8][kFeat][32].
// Thread T -> (row r = T>>5, slice s = (T>>2)&7, quarter q = T&3):
// reads 8 f32 (32B), writes uint4 (8 f16).
__global__ void cvt_sliced(const float* __restrict__ src,
                           uint4* __restrict__ dst) {
  const int total  = kFeat * 32;
  const int stride = gridDim.x * blockDim.x;
  for (int T = blockIdx.x * blockDim.x + threadIdx.x; T < total; T += stride) {
    const int r = T >> 5, s = (T >> 2) & 7, q = T & 3;
    const float4* p = (const float4*)(src + (size_t)r * 256 + s * 32 + q * 8);
    const float4 fa = p[0], fb = p[1];
    uint4 o;
    o.x = __builtin_bit_cast(unsigned, __floats2half2_rn(fa.x, fa.y));
    o.y = __builtin_bit_cast(unsigned, __floats2half2_rn(fa.z, fa.w));
    o.z = __builtin_bit_cast(unsigned, __floats2half2_rn(fb.x, fb.y));
    o.w = __builtin_bit_cast(unsigned, __floats2half2_rn(fb.z, fb.w));
    dst[(size_t)(s * kFeat + r) * 4 + q] = o;
  }
}

// Plain f32 table -> f16 row-major (for the fused fallback path)
__global__ void cvt_emb(const float4* __restrict__ src, uint2* __restrict__ dst) {
  const int n4 = kFeat * kHidden / 4;
  const int stride = gridDim.x * blockDim.x;
  for (int i = blockIdx.x * blockDim.x + threadIdx.x; i < n4; i += stride) {
    const float4 v = src[i];
    union { __half2 h[2]; uint2 u; } P;
    P.h[0] = __floats2half2_rn(v.x, v.y);
    P.h[1] = __floats2half2_rn(v.z, v.w);
    dst[i] = P.u;
  }
}

// ---------------------------------------------------------------------------
// Gather kernel: one wave x one (element, slice) task per iteration.
// Lane = (row-group g = lane>>2 in [0,16), quarter q = lane&3).
// Per task: rows {g, g+16} us + {g, g+16} them, 64B row-slices; reduce-
// scatter over lane bits 2-5; clipped f16 x stored (lanes 0-31).
constexpr int kGBlocks  = 2048;                       // 8 slices x 256 chunks
constexpr int kGTpb     = 256;                        // 4 waves
constexpr int kGChunk   = kBatch / (kGBlocks / kSlices);  // 512 elems/block
constexpr int kGPerWave = kGChunk / 4;                // 128
static_assert(kGChunk * (kGBlocks / kSlices) == kBatch);

__global__ __launch_bounds__(kGTpb, 8) void nnue_gather(
    const int* __restrict__ idx_us, const int* __restrict__ idx_th,
    const __half* __restrict__ embs, __half* __restrict__ x) {
  const int s     = blockIdx.x & 7;     // slice == XCD (round-robin dispatch)
  const int chunk = blockIdx.x >> 3;
  const int t    = threadIdx.x;
  const int lane = t & 63;
  const int g = lane >> 2, q = lane & 3;
  const u32x4* sbase =
      (const u32x4*)((const char*)embs + (size_t)s * kSliceBytes);
  unsigned* xw = (unsigned*)x;

  // dim this lane ends up holding (within the 32-dim slice), and its x word
  const int d = q * 8 + ((lane >> 2) & 1) * 4 + ((lane >> 3) & 1) * 2;
  const int wordoff = (lane < 16 ? 0 : 128) + s * 16 + (d >> 1);

  const int b0 = chunk * kGChunk + (t >> 6) * kGPerWave;
  for (int e = 0; e < kGPerWave; ++e) {
    const int b  = b0 + e;
    const int ib = b * kBag;
    const int iu0 = __builtin_nontemporal_load(idx_us + ib + g);
    const int iu1 = __builtin_nontemporal_load(idx_us + ib + 16 + g);
    const int it0 = __builtin_nontemporal_load(idx_th + ib + g);
    const int it1 = __builtin_nontemporal_load(idx_th + ib + 16 + g);
    const u32x4 v0 = sbase[iu0 * 4 + q];
    const u32x4 v1 = sbase[iu1 * 4 + q];
    const u32x4 v2 = sbase[it0 * 4 + q];
    const u32x4 v3 = sbase[it1 * 4 + q];
    unsigned aU[4] = {pkadd(v0.x, v1.x), pkadd(v0.y, v1.y),
                      pkadd(v0.z, v1.z), pkadd(v0.w, v1.w)};
    unsigned aT[4] = {pkadd(v2.x, v3.x), pkadd(v2.y, v3.y),
                      pkadd(v2.z, v3.z), pkadd(v2.w, v3.w)};
    // reduce-scatter over row-groups: xor4 (4->2 regs), xor8 (2->1), then
    // full sums at xor16/xor32.
    {
      const bool up = (lane & 4) != 0;
#pragma unroll
      for (int i = 0; i < 2; ++i) {
        unsigned sU = up ? aU[i] : aU[i + 2];
        unsigned sT = up ? aT[i] : aT[i + 2];
        sU = (unsigned)__shfl_xor((int)sU, 4, 64);
        sT = (unsigned)__shfl_xor((int)sT, 4, 64);
        aU[i] = pkadd(up ? aU[i + 2] : aU[i], sU);
        aT[i] = pkadd(up ? aT[i + 2] : aT[i], sT);
      }
    }
    {
      const bool up = (lane & 8) != 0;
      unsigned sU = up ? aU[0] : aU[1];
      unsigned sT = up ? aT[0] : aT[1];
      sU = (unsigned)__shfl_xor((int)sU, 8, 64);
      sT = (unsigned)__shfl_xor((int)sT, 8, 64);
      aU[0] = pkadd(up ? aU[1] : aU[0], sU);
      aT[0] = pkadd(up ? aT[1] : aT[0], sT);
    }
    aU[0] = pkadd(aU[0], (unsigned)__shfl_xor((int)aU[0], 16, 64));
    aT[0] = pkadd(aT[0], (unsigned)__shfl_xor((int)aT[0], 16, 64));
    aU[0] = pkadd(aU[0], (unsigned)__shfl_xor((int)aU[0], 32, 64));
    aT[0] = pkadd(aT[0], (unsigned)__shfl_xor((int)aT[0], 32, 64));

    if (lane < 32) {
      const unsigned val = pkclip(lane < 16 ? aU[0] : aT[0]);
      __builtin_nontemporal_store(val, xw + (size_t)b * 256 + wordoff);
    }
  }
}

// ---------------------------------------------------------------------------
// MLP kernel: x (pre-clipped f16 [B][512]) -> layers 1-3.
constexpr int kMBlocks = 1024;
constexpr int kMTpb    = 256;
constexpr int kMWpb    = kMTpb / 64;                  // 4
constexpr int kMElems  = kBatch / (kMBlocks * kMWpb); // 32
static_assert(kBatch % (kMBlocks * kMWpb) == 0);

__device__ __forceinline__ void mlp_tail(
    const __half* __restrict__ sW1h, __half* __restrict__ sy1row,
    const unsigned (&x2)[4], const unsigned (&w2h)[16],
    float b1r, float b2r, float wor, float outb,
    int lane, int myj, float* __restrict__ out, int b) {
  float p[32];
#pragma unroll
  for (int j = 0; j < 32; ++j) {
    const uint4 wv = *(const uint4*)&sW1h[(j * 64 + lane) * 8];
    float s = fdot2w(wv.x, x2[0], 0.0f);
    s = fdot2w(wv.y, x2[1], s);
    s = fdot2w(wv.z, x2[2], s);
    s = fdot2w(wv.w, x2[3], s);
    p[j] = s;
  }
  const float y1 = clip1(reduce32(p, lane) + b1r);  // lanes 2j,2j+1 hold y1[j]

  if ((lane & 1) == 0) sy1row[myj] = __float2half(y1);
  asm volatile("s_waitcnt lgkmcnt(0)" ::: "memory");

  const uint4* yv = (const uint4*)sy1row;  // 64B broadcast reads
  float y2 = b2r;
#pragma unroll
  for (int k4 = 0; k4 < 4; ++k4) {
    const uint4 y = yv[k4];
    y2 = fdot2w(w2h[4 * k4 + 0], y.x, y2);
    y2 = fdot2w(w2h[4 * k4 + 1], y.y, y2);
    y2 = fdot2w(w2h[4 * k4 + 2], y.z, y2);
    y2 = fdot2w(w2h[4 * k4 + 3], y.w, y2);
  }
  y2 = clip1(y2);

  float acc = y2 * wor;
#pragma unroll
  for (int d = 1; d < 32; d <<= 1) acc += __shfl_xor(acc, d, 64);
  if (lane == 0) out[b] = acc + outb;
}

__global__ __launch_bounds__(kMTpb, 4) void nnue_mlp(
    const __half* __restrict__ x, const float* __restrict__ w1,
    const float* __restrict__ b1, const float* __restrict__ w2,
    const float* __restrict__ b2, const float* __restrict__ wo,
    const float* __restrict__ bo, float* __restrict__ out) {
  __shared__ __align__(16) __half sW1h[32 * 512];   // 32 KB
  __shared__ __align__(16) __half sY1h[kMWpb][32];

  const int t = threadIdx.x;
  {  // stage W1 as f16
    const float4* src = (const float4*)w1;
#pragma unroll
    for (int c = 0; c < 16; ++c) {
      const float4 v = src[t * 16 + c];
      __half2* d = (__half2*)&sW1h[t * 64 + 4 * c];
      d[0] = __floats2half2_rn(v.x, v.y);
      d[1] = __floats2half2_rn(v.z, v.w);
    }
  }
  __syncthreads();

  const int lane   = t & 63;
  const int wlocal = t >> 6;
  const int wid    = blockIdx.x * kMWpb + wlocal;
  const int myj    = lane >> 1;
  const int j2     = lane & 31;

  const float b1r  = b1[myj];
  const float b2r  = b2[j2];
  const float wor  = wo[j2];
  const float outb = bo[0];
  unsigned w2h[16];
#pragma unroll
  for (int k = 0; k < 16; ++k) {
    w2h[k] = __builtin_bit_cast(
        unsigned, __floats2half2_rn(w2[j2 * 32 + 2 * k], w2[j2 * 32 + 2 * k + 1]));
  }

  const u32x4* xq = (const u32x4*)x;
  for (int e = 0; e < kMElems; ++e) {
    const int b = wid * kMElems + e;
    const u32x4 xv = __builtin_nontemporal_load(xq + (size_t)b * 64 + lane);
    const unsigned x2[4] = {xv.x, xv.y, xv.z, xv.w};
    mlp_tail(sW1h, &sY1h[wlocal][0], x2, w2h, b1r, b2r, wor, outb, lane, myj,
             out, b);
  }
}

// ---------------------------------------------------------------------------
// Fused fallback (R6): used when ws holds the f16 table but not x.
constexpr int kBlocksH = 1024;
constexpr int kTpb     = 256;
constexpr int kWpb     = kTpb / 64;
constexpr int kElemsH  = kBatch / (kBlocksH * kWpb);      // 32
constexpr int kPairs   = kElemsH / 2;

__global__ __launch_bounds__(kTpb, 4) void nnue_fwd_h(
    const int* __restrict__ idx_us, const int* __restrict__ idx_th,
    const __half* __restrict__ embh, const float* __restrict__ w1,
    const float* __restrict__ b1, const float* __restrict__ w2,
    const float* __restrict__ b2, const float* __restrict__ wo,
    const float* __restrict__ bo, float* __restrict__ out) {
  __shared__ __align__(16) __half sW1h[32 * 512];
  __shared__ __align__(16) __half sY1h[kWpb][32];

  const int t = threadIdx.x;
  {
    const float4* src = (const float4*)w1;
#pragma unroll
    for (int c = 0; c < 16; ++c) {
      const float4 v = src[t * 16 + c];
      __half2* d = (__half2*)&sW1h[t * 64 + 4 * c];
      d[0] = __floats2half2_rn(v.x, v.y);
      d[1] = __floats2half2_rn(v.z, v.w);
    }
  }
  __syncthreads();

  const int lane    = t & 63;
  const int wlocal  = t >> 6;
  const int wid     = blockIdx.x * kWpb + wlocal;
  const int myj     = lane >> 1;
  const int j2      = lane & 31;
  const int half31  = lane & 31;
  const bool hiHalf = lane >= 32;
  const uint4* embq = (const uint4*)embh;

  const float b1r  = b1[myj];
  const float b2r  = b2[j2];
  const float wor  = wo[j2];
  const float outb = bo[0];
  unsigned w2h[16];
#pragma unroll
  for (int k = 0; k < 16; ++k) {
    w2h[k] = __builtin_bit_cast(
        unsigned, __floats2half2_rn(w2[j2 * 32 + 2 * k], w2[j2 * 32 + 2 * k + 1]));
  }

  for (int e = 0; e < kPairs; ++e) {
    const int b0 = wid * kElemsH + 2 * e;
    const int b1i = b0 + 1;
    const int* ip0 = (lane < kBag) ? (idx_us + (size_t)b0 * kBag + lane)
                                   : (idx_th + (size_t)b0 * kBag + (lane - kBag));
    const int* ip1 = (lane < kBag) ? (idx_us + (size_t)b1i * kBag + lane)
                                    : (idx_th + (size_t)b1i * kBag + (lane - kBag));
    const int vidx0 = *ip0;
    const int vidx1 = *ip1;

    unsigned A0[8] = {0, 0, 0, 0, 0, 0, 0, 0};
    unsigned T0[8] = {0, 0, 0, 0, 0, 0, 0, 0};
    unsigned A1[8] = {0, 0, 0, 0, 0, 0, 0, 0};
    unsigned T1[8] = {0, 0, 0, 0, 0, 0, 0, 0};
#pragma unroll
    for (int s = 0; s < 16; ++s) {
      const int r0A = __builtin_amdgcn_readlane(vidx0, 2 * s);
      const int r0B = __builtin_amdgcn_readlane(vidx0, 2 * s + 1);
      const int r1A = __builtin_amdgcn_readlane(vidx1, 2 * s);
      const int r1B = __builtin_amdgcn_readlane(vidx1, 2 * s + 1);
      const uint4 v0 = embq[(size_t)(hiHalf ? r0B : r0A) * 32 + half31];
      const uint4 v1 = embq[(size_t)(hiHalf ? r1B : r1A) * 32 + half31];
      const int o = (s & 1) * 4;
      A0[o + 0] = pkadd(A0[o + 0], v0.x);
      A0[o + 1] = pkadd(A0[o + 1], v0.y);
      A0[o + 2] = pkadd(A0[o + 2], v0.z);
      A0[o + 3] = pkadd(A0[o + 3], v0.w);
      A1[o + 0] = pkadd(A1[o + 0], v1.x);
      A1[o + 1] = pkadd(A1[o + 1], v1.y);
      A1[o + 2] = pkadd(A1[o + 2], v1.z);
      A1[o + 3] = pkadd(A1[o + 3], v1.w);
    }
#pragma unroll
    for (int s = 0; s < 16; ++s) {
      const int r0A = __builtin_amdgcn_readlane(vidx0, 32 + 2 * s);
      const int r0B = __builtin_amdgcn_readlane(vidx0, 33 + 2 * s);
      const int r1A = __builtin_amdgcn_readlane(vidx1, 32 + 2 * s);
      const int r1B = __builtin_amdgcn_readlane(vidx1, 33 + 2 * s);
      const uint4 v0 = embq[(size_t)(hiHalf ? r0B : r0A) * 32 + half31];
      const uint4 v1 = embq[(size_t)(hiHalf ? r1B : r1A) * 32 + half31];
      const int o = (s & 1) * 4;
      T0[o + 0] = pkadd(T0[o + 0], v0.x);
      T0[o + 1] = pkadd(T0[o + 1], v0.y);
      T0[o + 2] = pkadd(T0[o + 2], v0.z);
      T0[o + 3] = pkadd(T0[o + 3], v0.w);
      T1[o + 0] = pkadd(T1[o + 0], v1.x);
      T1[o + 1] = pkadd(T1[o + 1], v1.y);
      T1[o + 2] = pkadd(T1[o + 2], v1.z);
      T1[o + 3] = pkadd(T1[o + 3], v1.w);
    }

    unsigned x20[4], x21[4];
#pragma unroll
    for (int q = 0; q < 4; ++q) {
      unsigned u0 = pkadd(A0[q], A0[q + 4]);
      unsigned t0 = pkadd(T0[q], T0[q + 4]);
      unsigned u1 = pkadd(A1[q], A1[q + 4]);
      unsigned t1 = pkadd(T1[q], T1[q + 4]);
      u0 = pkadd(u0, (unsigned)__shfl_xor((int)u0, 32, 64));
      t0 = pkadd(t0, (unsigned)__shfl_xor((int)t0, 32, 64));
      u1 = pkadd(u1, (unsigned)__shfl_xor((int)u1, 32, 64));
      t1 = pkadd(t1, (unsigned)__shfl_xor((int)t1, 32, 64));
      x20[q] = pkclip(hiHalf ? t0 : u0);
      x21[q] = pkclip(hiHalf ? t1 : u1);
    }

    mlp_tail(sW1h, &sY1h[wlocal][0], x20, w2h, b1r, b2r, wor, outb, lane, myj,
             out, b0);
    mlp_tail(sW1h, &sY1h[wlocal][0], x21, w2h, b1r, b2r, wor, outb, lane, myj,
             out, b1i);
  }
}

// ---------------------------------------------------------------------------
// f32 fallback
constexpr int kTpbF    = 256;
constexpr int kWpbF    = kTpbF / 64;
constexpr int kBlocksF = 512;
constexpr int kElemsF  = kBatch / (kBlocksF * kWpbF);

__global__ __launch_bounds__(kTpbF, 2) void nnue_fwd_f32(
    const int* __restrict__ idx_us, const int* __restrict__ idx_th,
    const float* __restrict__ emb, const float* __restrict__ w1,
    const float* __restrict__ b1, const float* __restrict__ w2,
    const float* __restrict__ b2, const float* __restrict__ wo,
    const float* __restrict__ bo, float* __restrict__ out) {
  __shared__ float sW1[32][512];
  __shared__ __align__(16) float sY1[kWpbF][32];

  const int t = threadIdx.x;
  {
    const float4* src = (const float4*)w1;
    float4* dst = (float4*)&sW1[0][0];
#pragma unroll
    for (int i = 0; i < 16; ++i) dst[i * kTpbF + t] = src[i * kTpbF + t];
  }
  __syncthreads();

  const int lane   = t & 63;
  const int wlocal = t >> 6;
  const int wid    = blockIdx.x * kWpbF + wlocal;
  const int myj    = lane >> 1;
  const int j2     = lane & 31;

  const float b1r  = b1[myj];
  const float b2r  = b2[j2];
  const float wor  = wo[j2];
  const float outb = bo[0];
  float w2r[32];
#pragma unroll
  for (int k = 0; k < 32; ++k) w2r[k] = w2[j2 * 32 + k];

  for (int e = 0; e < kElemsF; ++e) {
    const int b = wid * kElemsF + e;
    const int* ip = (lane < kBag) ? (idx_us + (size_t)b * kBag + lane)
                                  : (idx_th + (size_t)b * kBag + (lane - kBag));
    const int vidx = *ip;

    float4 au = make_float4(0.f, 0.f, 0.f, 0.f);
    float4 at = make_float4(0.f, 0.f, 0.f, 0.f);
#pragma unroll
    for (int i = 0; i < kBag; ++i) {
      const int iu = __builtin_amdgcn_readlane(vidx, i);
      const float4 v = ((const float4*)(emb + (size_t)iu * kHidden))[lane];
      au.x += v.x; au.y += v.y; au.z += v.z; au.w += v.w;
    }
#pragma unroll
    for (int i = 0; i < kBag; ++i) {
      const int it2 = __builtin_amdgcn_readlane(vidx, i + kBag);
      const float4 v = ((const float4*)(emb + (size_t)it2 * kHidden))[lane];
      at.x += v.x; at.y += v.y; at.z += v.z; at.w += v.w;
    }

    au.x = clip1(au.x); au.y = clip1(au.y); au.z = clip1(au.z); au.w = clip1(au.w);
    at.x = clip1(at.x); at.y = clip1(at.y); at.z = clip1(at.z); at.w = clip1(at.w);

    float p[32];
#pragma unroll
    for (int j = 0; j < 32; ++j) {
      const float4 a = *(const float4*)&sW1[j][4 * lane];
      const float4 c = *(const float4*)&sW1[j][kHidden + 4 * lane];
      p[j] = au.x * a.x + au.y * a.y + au.z * a.z + au.w * a.w +
             at.x * c.x + at.y * c.y + at.z * c.z + at.w * c.w;
    }
    const float y1 = clip1(reduce32(p, lane) + b1r);

    if ((lane & 1) == 0) sY1[wlocal][myj] = y1;
    asm volatile("s_waitcnt lgkmcnt(0)" ::: "memory");

    const float4* y4 = (const float4*)&sY1[wlocal][0];
    float y2 = b2r;
#pragma unroll
    for (int k4 = 0; k4 < 8; ++k4) {
      const float4 y = y4[k4];
      y2 += w2r[4 * k4 + 0] * y.x + w2r[4 * k4 + 1] * y.y +
            w2r[4 * k4 + 2] * y.z + w2r[4 * k4 + 3] * y.w;
    }
    y2 = clip1(y2);

    float acc = y2 * wor;
#pragma unroll
    for (int d = 1; d < 32; d <<= 1) acc += __shfl_xor(acc, d, 64);
    if (lane == 0) out[b] = acc + outb;
  }
}

extern "C" void kernel_launch(void* const* d_in, const int* in_sizes, int n_in,
                              void* d_out, int out_size, void* d_ws, size_t ws_size,
                              hipStream_t stream) {
  const int* idx_us  = (const int*)d_in[0];
  const int* idx_th  = (const int*)d_in[1];
  const float* emb   = (const float*)d_in[2];
  const float* w1    = (const float*)d_in[3];
  const float* b1    = (const float*)d_in[4];
  const float* w2    = (const float*)d_in[5];
  const float* b2    = (const float*)d_in[6];
  const float* wo    = (const float*)d_in[7];
  const float* bo    = (const float*)d_in[8];
  float* out         = (float*)d_out;

  if (ws_size >= kEmbsBytes + kXBytes) {
    __half* embs = (__half*)d_ws;
    __half* x    = (__half*)((char*)d_ws + kEmbsBytes);
    cvt_sliced<<<2560, 256, 0, stream>>>(emb, (uint4*)embs);
    nnue_gather<<<kGBlocks, kGTpb, 0, stream>>>(idx_us, idx_th, embs, x);
    nnue_mlp<<<kMBlocks, kMTpb, 0, stream>>>(x, w1, b1, w2, b2, wo, bo, out);
  } else if (ws_size >= kEmbsBytes) {
    __half* embh = (__half*)d_ws;
    cvt_emb<<<2048, 256, 0, stream>>>((const float4*)emb, (uint2*)embh);
    nnue_fwd_h<<<kBlocksH, kTpb, 0, stream>>>(idx_us, idx_th, embh, w1, b1, w2,
                                              b2, wo, bo, out);
  } else {
    nnue_fwd_f32<<<kBlocksF, kTpbF, 0, stream>>>(idx_us, idx_th, emb, w1, b1,
                                                 w2, b2, wo, bo, out);
  }
}

// Round 9
// 399.351 us; speedup vs baseline: 1.5200x; 1.5200x over previous
//
#include <hip/hip_runtime.h>
#include <hip/hip_fp16.h>

// NNUE forward: embedding-bag (2x32 gathers of 256-dim rows) -> clipped relu
// -> 512->32->32->1 MLP.
//
// R9: latency fixes on the R8 split design. R8 gather: FETCH dropped 12x
// (XCD-L2 placement works) but dur flat at 494us, VGPR=16, VALUBusy 17% ->
// serial chains: nt idx loads bypassed L2/L3 (HBM ~900cy each), no unroll.
// Changes:
//  - idx: ONE full-wave plain load (L3-cacheable) + 4 __shfl to distribute
//  - 2-element manual unroll, launch_bounds(256,4) for VGPR headroom
//  - x store stays nontemporal (don't evict the L2 table slice)
//  - MLP: 2 elements per pass sharing each W1 ds_read_b128

constexpr int kBatch  = 131072;
constexpr int kHidden = 256;
constexpr int kBag    = 32;
constexpr int kFeat   = 40960;

constexpr int    kSlices     = 8;
constexpr int    kSliceDims  = 32;                                   // cols/slice
constexpr size_t kSliceBytes = (size_t)kFeat * kSliceDims * 2;       // 2.62 MB
constexpr size_t kEmbsBytes  = kSliceBytes * kSlices;                // 21 MB
constexpr size_t kXBytes     = (size_t)kBatch * 2 * kHidden * 2;     // 134 MB

typedef unsigned u32x4 __attribute__((ext_vector_type(4)));

__device__ __forceinline__ float clip1(float x) {
  return fminf(fmaxf(x, 0.0f), 1.0f);  // v_med3_f32
}

typedef _Float16 h2_t __attribute__((ext_vector_type(2)));

__device__ __forceinline__ unsigned pkadd(unsigned a, unsigned b) {
  const h2_t r = __builtin_bit_cast(h2_t, a) + __builtin_bit_cast(h2_t, b);
  return __builtin_bit_cast(unsigned, r);  // v_pk_add_f16
}

__device__ __forceinline__ unsigned pkclip(unsigned a) {
  unsigned r;
  const unsigned zero = 0u;            // {0.0h, 0.0h}
  const unsigned one  = 0x3C003C00u;   // {1.0h, 1.0h}
  asm("v_pk_max_f16 %0, %1, %2\n\t"
      "v_pk_min_f16 %0, %0, %3"
      : "=&v"(r)
      : "v"(a), "v"(zero), "v"(one));
  return r;
}

// v_dot2_f32_f16: c += a.x*b.x + a.y*b.y (f32 accumulate, f16 inputs)
__device__ __forceinline__ float fdot2w(unsigned a, unsigned b, float c) {
  return __builtin_amdgcn_fdot2(__builtin_bit_cast(h2_t, a),
                                __builtin_bit_cast(h2_t, b), c, false);
}

// One butterfly reduce-scatter stage; ALL indices compile-time constants.
template <int D, int HALF>
__device__ __forceinline__ void rs_stage(float (&p)[32], int lane) {
  const bool up = (lane & D) != 0;
#pragma unroll
  for (int i = 0; i < HALF; ++i) {
    const float send = up ? p[i] : p[i + HALF];
    const float recv = __shfl_xor(send, D, 64);
    p[i] = (up ? p[i + HALF] : p[i]) + recv;
  }
}

__device__ __forceinline__ float reduce32(float (&p)[32], int lane) {
  rs_stage<32, 16>(p, lane);
  rs_stage<16, 8>(p, lane);
  rs_stage<8, 4>(p, lane);
  rs_stage<4, 2>(p, lane);
  rs_stage<2, 1>(p, lane);
  return p[0] + __shfl_xor(p[0], 1, 64);
}

// ---------------------------------------------------------------------------
// Table repack: f32 [kFeat][256] -> f16 sliced [8][kFeat][32].
__global__ void cvt_sliced(const float* __restrict__ src,
                           uint4* __restrict__ dst) {
  const int total  = kFeat * 32;
  const int stride = gridDim.x * blockDim.x;
  for (int T = blockIdx.x * blockDim.x + threadIdx.x; T < total; T += stride) {
    const int r = T >> 5, s = (T >> 2) & 7, q = T & 3;
    const float4* p = (const float4*)(src + (size_t)r * 256 + s * 32 + q * 8);
    const float4 fa = p[0], fb = p[1];
    uint4 o;
    o.x = __builtin_bit_cast(unsigned, __floats2half2_rn(fa.x, fa.y));
    o.y = __builtin_bit_cast(unsigned, __floats2half2_rn(fa.z, fa.w));
    o.z = __builtin_bit_cast(unsigned, __floats2half2_rn(fb.x, fb.y));
    o.w = __builtin_bit_cast(unsigned, __floats2half2_rn(fb.z, fb.w));
    dst[(size_t)(s * kFeat + r) * 4 + q] = o;
  }
}

// Plain f32 table -> f16 row-major (for the fused fallback path)
__global__ void cvt_emb(const float4* __restrict__ src, uint2* __restrict__ dst) {
  const int n4 = kFeat * kHidden / 4;
  const int stride = gridDim.x * blockDim.x;
  for (int i = blockIdx.x * blockDim.x + threadIdx.x; i < n4; i += stride) {
    const float4 v = src[i];
    union { __half2 h[2]; uint2 u; } P;
    P.h[0] = __floats2half2_rn(v.x, v.y);
    P.h[1] = __floats2half2_rn(v.z, v.w);
    dst[i] = P.u;
  }
}

// ---------------------------------------------------------------------------
// Gather kernel.
constexpr int kGBlocks  = 2048;                       // 8 slices x 256 chunks
constexpr int kGTpb     = 256;                        // 4 waves
constexpr int kGChunk   = kBatch / (kGBlocks / kSlices);  // 512 elems/block
constexpr int kGPerWave = kGChunk / 4;                // 128
static_assert(kGChunk * (kGBlocks / kSlices) == kBatch);

// Reduce one element's 4 row-slice vectors (us-lo/us-hi/th-lo/th-hi quarter
// loads) across the 16 row-groups; returns {usWord, themWord} summed.
__device__ __forceinline__ void bag_reduce(const u32x4 v0, const u32x4 v1,
                                           const u32x4 v2, const u32x4 v3,
                                           int lane, unsigned& U, unsigned& T) {
  unsigned aU[4] = {pkadd(v0.x, v1.x), pkadd(v0.y, v1.y),
                    pkadd(v0.z, v1.z), pkadd(v0.w, v1.w)};
  unsigned aT[4] = {pkadd(v2.x, v3.x), pkadd(v2.y, v3.y),
                    pkadd(v2.z, v3.z), pkadd(v2.w, v3.w)};
  {
    const bool up = (lane & 4) != 0;
#pragma unroll
    for (int i = 0; i < 2; ++i) {
      unsigned sU = up ? aU[i] : aU[i + 2];
      unsigned sT = up ? aT[i] : aT[i + 2];
      sU = (unsigned)__shfl_xor((int)sU, 4, 64);
      sT = (unsigned)__shfl_xor((int)sT, 4, 64);
      aU[i] = pkadd(up ? aU[i + 2] : aU[i], sU);
      aT[i] = pkadd(up ? aT[i + 2] : aT[i], sT);
    }
  }
  {
    const bool up = (lane & 8) != 0;
    unsigned sU = up ? aU[0] : aU[1];
    unsigned sT = up ? aT[0] : aT[1];
    sU = (unsigned)__shfl_xor((int)sU, 8, 64);
    sT = (unsigned)__shfl_xor((int)sT, 8, 64);
    aU[0] = pkadd(up ? aU[1] : aU[0], sU);
    aT[0] = pkadd(up ? aT[1] : aT[0], sT);
  }
  aU[0] = pkadd(aU[0], (unsigned)__shfl_xor((int)aU[0], 16, 64));
  aT[0] = pkadd(aT[0], (unsigned)__shfl_xor((int)aT[0], 16, 64));
  aU[0] = pkadd(aU[0], (unsigned)__shfl_xor((int)aU[0], 32, 64));
  aT[0] = pkadd(aT[0], (unsigned)__shfl_xor((int)aT[0], 32, 64));
  U = aU[0];
  T = aT[0];
}

__global__ __launch_bounds__(kGTpb, 4) void nnue_gather(
    const int* __restrict__ idx_us, const int* __restrict__ idx_th,
    const __half* __restrict__ embs, __half* __restrict__ x) {
  const int s     = blockIdx.x & 7;     // slice == XCD (round-robin dispatch)
  const int chunk = blockIdx.x >> 3;
  const int t    = threadIdx.x;
  const int lane = t & 63;
  const int g = lane >> 2, q = lane & 3;
  const u32x4* sbase =
      (const u32x4*)((const char*)embs + (size_t)s * kSliceBytes);
  unsigned* xw = (unsigned*)x;

  // dim this lane ends up holding (within the 32-dim slice), and its x word
  const int d = q * 8 + ((lane >> 2) & 1) * 4 + ((lane >> 3) & 1) * 2;
  const int wordoff = (lane < 16 ? 0 : 128) + s * 16 + (d >> 1);

  // one full-wave idx load: lanes 0-31 <- us[b][lane], 32-63 <- them[b][l-32]
  const int idxsel = lane & 31;
  const int* idxbase = (lane < 32) ? idx_us : idx_th;

  const int b0w = chunk * kGChunk + (t >> 6) * kGPerWave;
  for (int e = 0; e < kGPerWave; e += 2) {
    const int bA = b0w + e;
    const int bB = bA + 1;
    const int iA = idxbase[(size_t)bA * kBag + idxsel];
    const int iB = idxbase[(size_t)bB * kBag + idxsel];
    // distribute the 4 row numbers this lane needs (rows g, g+16 of each side)
    const int rA0 = __shfl(iA, g, 64);
    const int rA1 = __shfl(iA, 16 + g, 64);
    const int rA2 = __shfl(iA, 32 + g, 64);
    const int rA3 = __shfl(iA, 48 + g, 64);
    const int rB0 = __shfl(iB, g, 64);
    const int rB1 = __shfl(iB, 16 + g, 64);
    const int rB2 = __shfl(iB, 32 + g, 64);
    const int rB3 = __shfl(iB, 48 + g, 64);
    // issue all 8 table loads before either reduce chain
    const u32x4 vA0 = sbase[rA0 * 4 + q];
    const u32x4 vA1 = sbase[rA1 * 4 + q];
    const u32x4 vA2 = sbase[rA2 * 4 + q];
    const u32x4 vA3 = sbase[rA3 * 4 + q];
    const u32x4 vB0 = sbase[rB0 * 4 + q];
    const u32x4 vB1 = sbase[rB1 * 4 + q];
    const u32x4 vB2 = sbase[rB2 * 4 + q];
    const u32x4 vB3 = sbase[rB3 * 4 + q];

    unsigned UA, TA, UB, TB;
    bag_reduce(vA0, vA1, vA2, vA3, lane, UA, TA);
    bag_reduce(vB0, vB1, vB2, vB3, lane, UB, TB);

    if (lane < 32) {
      const unsigned valA = pkclip(lane < 16 ? UA : TA);
      const unsigned valB = pkclip(lane < 16 ? UB : TB);
      __builtin_nontemporal_store(valA, xw + (size_t)bA * 256 + wordoff);
      __builtin_nontemporal_store(valB, xw + (size_t)bB * 256 + wordoff);
    }
  }
}

// ---------------------------------------------------------------------------
// MLP kernel: x (pre-clipped f16 [B][512]) -> layers 1-3.
// 2 elements per pass sharing each W1 ds_read_b128.
constexpr int kMBlocks = 1024;
constexpr int kMTpb    = 256;
constexpr int kMWpb    = kMTpb / 64;                  // 4
constexpr int kMElems  = kBatch / (kMBlocks * kMWpb); // 32
static_assert(kBatch % (kMBlocks * kMWpb) == 0);

__global__ __launch_bounds__(kMTpb, 4) void nnue_mlp(
    const __half* __restrict__ x, const float* __restrict__ w1,
    const float* __restrict__ b1, const float* __restrict__ w2,
    const float* __restrict__ b2, const float* __restrict__ wo,
    const float* __restrict__ bo, float* __restrict__ out) {
  __shared__ __align__(16) __half sW1h[32 * 512];      // 32 KB
  __shared__ __align__(16) __half sY1h[kMWpb][2][32];  // 2 rows per wave

  const int t = threadIdx.x;
  {  // stage W1 as f16
    const float4* src = (const float4*)w1;
#pragma unroll
    for (int c = 0; c < 16; ++c) {
      const float4 v = src[t * 16 + c];
      __half2* d = (__half2*)&sW1h[t * 64 + 4 * c];
      d[0] = __floats2half2_rn(v.x, v.y);
      d[1] = __floats2half2_rn(v.z, v.w);
    }
  }
  __syncthreads();

  const int lane   = t & 63;
  const int wlocal = t >> 6;
  const int wid    = blockIdx.x * kMWpb + wlocal;
  const int myj    = lane >> 1;
  const int j2     = lane & 31;

  const float b1r  = b1[myj];
  const float b2r  = b2[j2];
  const float wor  = wo[j2];
  const float outb = bo[0];
  unsigned w2h[16];
#pragma unroll
  for (int k = 0; k < 16; ++k) {
    w2h[k] = __builtin_bit_cast(
        unsigned, __floats2half2_rn(w2[j2 * 32 + 2 * k], w2[j2 * 32 + 2 * k + 1]));
  }

  const u32x4* xq = (const u32x4*)x;
  for (int e = 0; e < kMElems; e += 2) {
    const int b0 = wid * kMElems + e;
    const int b1i = b0 + 1;
    const u32x4 xv0 = __builtin_nontemporal_load(xq + (size_t)b0 * 64 + lane);
    const u32x4 xv1 = __builtin_nontemporal_load(xq + (size_t)b1i * 64 + lane);

    float p0[32], p1[32];
#pragma unroll
    for (int j = 0; j < 32; ++j) {
      const uint4 wv = *(const uint4*)&sW1h[(j * 64 + lane) * 8];  // shared
      float s0 = fdot2w(wv.x, xv0.x, 0.0f);
      float s1 = fdot2w(wv.x, xv1.x, 0.0f);
      s0 = fdot2w(wv.y, xv0.y, s0);
      s1 = fdot2w(wv.y, xv1.y, s1);
      s0 = fdot2w(wv.z, xv0.z, s0);
      s1 = fdot2w(wv.z, xv1.z, s1);
      s0 = fdot2w(wv.w, xv0.w, s0);
      s1 = fdot2w(wv.w, xv1.w, s1);
      p0[j] = s0;
      p1[j] = s1;
    }
    const float y10 = clip1(reduce32(p0, lane) + b1r);
    const float y11 = clip1(reduce32(p1, lane) + b1r);

    if ((lane & 1) == 0) {
      sY1h[wlocal][0][myj] = __float2half(y10);
      sY1h[wlocal][1][myj] = __float2half(y11);
    }
    asm volatile("s_waitcnt lgkmcnt(0)" ::: "memory");

    const uint4* yv0 = (const uint4*)&sY1h[wlocal][0][0];
    const uint4* yv1 = (const uint4*)&sY1h[wlocal][1][0];
    float y20 = b2r, y21 = b2r;
#pragma unroll
    for (int k4 = 0; k4 < 4; ++k4) {
      const uint4 ya = yv0[k4];
      const uint4 yb = yv1[k4];
      y20 = fdot2w(w2h[4 * k4 + 0], ya.x, y20);
      y21 = fdot2w(w2h[4 * k4 + 0], yb.x, y21);
      y20 = fdot2w(w2h[4 * k4 + 1], ya.y, y20);
      y21 = fdot2w(w2h[4 * k4 + 1], yb.y, y21);
      y20 = fdot2w(w2h[4 * k4 + 2], ya.z, y20);
      y21 = fdot2w(w2h[4 * k4 + 2], yb.z, y21);
      y20 = fdot2w(w2h[4 * k4 + 3], ya.w, y20);
      y21 = fdot2w(w2h[4 * k4 + 3], yb.w, y21);
    }
    y20 = clip1(y20);
    y21 = clip1(y21);

    float a0 = y20 * wor;
    float a1 = y21 * wor;
#pragma unroll
    for (int d = 1; d < 32; d <<= 1) {
      a0 += __shfl_xor(a0, d, 64);
      a1 += __shfl_xor(a1, d, 64);
    }
    if (lane == 0) {
      out[b0]  = a0 + outb;
      out[b1i] = a1 + outb;
    }
  }
}

// ---------------------------------------------------------------------------
// Fused fallback (R6): used when ws holds the f16 table but not x.
constexpr int kBlocksH = 1024;
constexpr int kTpb     = 256;
constexpr int kWpb     = kTpb / 64;
constexpr int kElemsH  = kBatch / (kBlocksH * kWpb);      // 32
constexpr int kPairs   = kElemsH / 2;

__device__ __forceinline__ void mlp_tail(
    const __half* __restrict__ sW1h, __half* __restrict__ sy1row,
    const unsigned (&x2)[4], const unsigned (&w2h)[16],
    float b1r, float b2r, float wor, float outb,
    int lane, int myj, float* __restrict__ out, int b) {
  float p[32];
#pragma unroll
  for (int j = 0; j < 32; ++j) {
    const uint4 wv = *(const uint4*)&sW1h[(j * 64 + lane) * 8];
    float s = fdot2w(wv.x, x2[0], 0.0f);
    s = fdot2w(wv.y, x2[1], s);
    s = fdot2w(wv.z, x2[2], s);
    s = fdot2w(wv.w, x2[3], s);
    p[j] = s;
  }
  const float y1 = clip1(reduce32(p, lane) + b1r);

  if ((lane & 1) == 0) sy1row[myj] = __float2half(y1);
  asm volatile("s_waitcnt lgkmcnt(0)" ::: "memory");

  const uint4* yv = (const uint4*)sy1row;
  float y2 = b2r;
#pragma unroll
  for (int k4 = 0; k4 < 4; ++k4) {
    const uint4 y = yv[k4];
    y2 = fdot2w(w2h[4 * k4 + 0], y.x, y2);
    y2 = fdot2w(w2h[4 * k4 + 1], y.y, y2);
    y2 = fdot2w(w2h[4 * k4 + 2], y.z, y2);
    y2 = fdot2w(w2h[4 * k4 + 3], y.w, y2);
  }
  y2 = clip1(y2);

  float acc = y2 * wor;
#pragma unroll
  for (int d = 1; d < 32; d <<= 1) acc += __shfl_xor(acc, d, 64);
  if (lane == 0) out[b] = acc + outb;
}

__global__ __launch_bounds__(kTpb, 4) void nnue_fwd_h(
    const int* __restrict__ idx_us, const int* __restrict__ idx_th,
    const __half* __restrict__ embh, const float* __restrict__ w1,
    const float* __restrict__ b1, const float* __restrict__ w2,
    const float* __restrict__ b2, const float* __restrict__ wo,
    const float* __restrict__ bo, float* __restrict__ out) {
  __shared__ __align__(16) __half sW1h[32 * 512];
  __shared__ __align__(16) __half sY1h[kWpb][32];

  const int t = threadIdx.x;
  {
    const float4* src = (const float4*)w1;
#pragma unroll
    for (int c = 0; c < 16; ++c) {
      const float4 v = src[t * 16 + c];
      __half2* d = (__half2*)&sW1h[t * 64 + 4 * c];
      d[0] = __floats2half2_rn(v.x, v.y);
      d[1] = __floats2half2_rn(v.z, v.w);
    }
  }
  __syncthreads();

  const int lane    = t & 63;
  const int wlocal  = t >> 6;
  const int wid     = blockIdx.x * kWpb + wlocal;
  const int myj     = lane >> 1;
  const int j2      = lane & 31;
  const int half31  = lane & 31;
  const bool hiHalf = lane >= 32;
  const uint4* embq = (const uint4*)embh;

  const float b1r  = b1[myj];
  const float b2r  = b2[j2];
  const float wor  = wo[j2];
  const float outb = bo[0];
  unsigned w2h[16];
#pragma unroll
  for (int k = 0; k < 16; ++k) {
    w2h[k] = __builtin_bit_cast(
        unsigned, __floats2half2_rn(w2[j2 * 32 + 2 * k], w2[j2 * 32 + 2 * k + 1]));
  }

  for (int e = 0; e < kPairs; ++e) {
    const int b0 = wid * kElemsH + 2 * e;
    const int b1i = b0 + 1;
    const int* ip0 = (lane < kBag) ? (idx_us + (size_t)b0 * kBag + lane)
                                   : (idx_th + (size_t)b0 * kBag + (lane - kBag));
    const int* ip1 = (lane < kBag) ? (idx_us + (size_t)b1i * kBag + lane)
                                    : (idx_th + (size_t)b1i * kBag + (lane - kBag));
    const int vidx0 = *ip0;
    const int vidx1 = *ip1;

    unsigned A0[8] = {0, 0, 0, 0, 0, 0, 0, 0};
    unsigned T0[8] = {0, 0, 0, 0, 0, 0, 0, 0};
    unsigned A1[8] = {0, 0, 0, 0, 0, 0, 0, 0};
    unsigned T1[8] = {0, 0, 0, 0, 0, 0, 0, 0};
#pragma unroll
    for (int s = 0; s < 16; ++s) {
      const int r0A = __builtin_amdgcn_readlane(vidx0, 2 * s);
      const int r0B = __builtin_amdgcn_readlane(vidx0, 2 * s + 1);
      const int r1A = __builtin_amdgcn_readlane(vidx1, 2 * s);
      const int r1B = __builtin_amdgcn_readlane(vidx1, 2 * s + 1);
      const uint4 v0 = embq[(size_t)(hiHalf ? r0B : r0A) * 32 + half31];
      const uint4 v1 = embq[(size_t)(hiHalf ? r1B : r1A) * 32 + half31];
      const int o = (s & 1) * 4;
      A0[o + 0] = pkadd(A0[o + 0], v0.x);
      A0[o + 1] = pkadd(A0[o + 1], v0.y);
      A0[o + 2] = pkadd(A0[o + 2], v0.z);
      A0[o + 3] = pkadd(A0[o + 3], v0.w);
      A1[o + 0] = pkadd(A1[o + 0], v1.x);
      A1[o + 1] = pkadd(A1[o + 1], v1.y);
      A1[o + 2] = pkadd(A1[o + 2], v1.z);
      A1[o + 3] = pkadd(A1[o + 3], v1.w);
    }
#pragma unroll
    for (int s = 0; s < 16; ++s) {
      const int r0A = __builtin_amdgcn_readlane(vidx0, 32 + 2 * s);
      const int r0B = __builtin_amdgcn_readlane(vidx0, 33 + 2 * s);
      const int r1A = __builtin_amdgcn_readlane(vidx1, 32 + 2 * s);
      const int r1B = __builtin_amdgcn_readlane(vidx1, 33 + 2 * s);
      const uint4 v0 = embq[(size_t)(hiHalf ? r0B : r0A) * 32 + half31];
      const uint4 v1 = embq[(size_t)(hiHalf ? r1B : r1A) * 32 + half31];
      const int o = (s & 1) * 4;
      T0[o + 0] = pkadd(T0[o + 0], v0.x);
      T0[o + 1] = pkadd(T0[o + 1], v0.y);
      T0[o + 2] = pkadd(T0[o + 2], v0.z);
      T0[o + 3] = pkadd(T0[o + 3], v0.w);
      T1[o + 0] = pkadd(T1[o + 0], v1.x);
      T1[o + 1] = pkadd(T1[o + 1], v1.y);
      T1[o + 2] = pkadd(T1[o + 2], v1.z);
      T1[o + 3] = pkadd(T1[o + 3], v1.w);
    }

    unsigned x20[4], x21[4];
#pragma unroll
    for (int q = 0; q < 4; ++q) {
      unsigned u0 = pkadd(A0[q], A0[q + 4]);
      unsigned t0 = pkadd(T0[q], T0[q + 4]);
      unsigned u1 = pkadd(A1[q], A1[q + 4]);
      unsigned t1 = pkadd(T1[q], T1[q + 4]);
      u0 = pkadd(u0, (unsigned)__shfl_xor((int)u0, 32, 64));
      t0 = pkadd(t0, (unsigned)__shfl_xor((int)t0, 32, 64));
      u1 = pkadd(u1, (unsigned)__shfl_xor((int)u1, 32, 64));
      t1 = pkadd(t1, (unsigned)__shfl_xor((int)t1, 32, 64));
      x20[q] = pkclip(hiHalf ? t0 : u0);
      x21[q] = pkclip(hiHalf ? t1 : u1);
    }

    mlp_tail(sW1h, &sY1h[wlocal][0], x20, w2h, b1r, b2r, wor, outb, lane, myj,
             out, b0);
    mlp_tail(sW1h, &sY1h[wlocal][0], x21, w2h, b1r, b2r, wor, outb, lane, myj,
             out, b1i);
  }
}

// ---------------------------------------------------------------------------
// f32 fallback
constexpr int kTpbF    = 256;
constexpr int kWpbF    = kTpbF / 64;
constexpr int kBlocksF = 512;
constexpr int kElemsF  = kBatch / (kBlocksF * kWpbF);

__global__ __launch_bounds__(kTpbF, 2) void nnue_fwd_f32(
    const int* __restrict__ idx_us, const int* __restrict__ idx_th,
    const float* __restrict__ emb, const float* __restrict__ w1,
    const float* __restrict__ b1, const float* __restrict__ w2,
    const float* __restrict__ b2, const float* __restrict__ wo,
    const float* __restrict__ bo, float* __restrict__ out) {
  __shared__ float sW1[32][512];
  __shared__ __align__(16) float sY1[kWpbF][32];

  const int t = threadIdx.x;
  {
    const float4* src = (const float4*)w1;
    float4* dst = (float4*)&sW1[0][0];
#pragma unroll
    for (int i = 0; i < 16; ++i) dst[i * kTpbF + t] = src[i * kTpbF + t];
  }
  __syncthreads();

  const int lane   = t & 63;
  const int wlocal = t >> 6;
  const int wid    = blockIdx.x * kWpbF + wlocal;
  const int myj    = lane >> 1;
  const int j2     = lane & 31;

  const float b1r  = b1[myj];
  const float b2r  = b2[j2];
  const float wor  = wo[j2];
  const float outb = bo[0];
  float w2r[32];
#pragma unroll
  for (int k = 0; k < 32; ++k) w2r[k] = w2[j2 * 32 + k];

  for (int e = 0; e < kElemsF; ++e) {
    const int b = wid * kElemsF + e;
    const int* ip = (lane < kBag) ? (idx_us + (size_t)b * kBag + lane)
                                  : (idx_th + (size_t)b * kBag + (lane - kBag));
    const int vidx = *ip;

    float4 au = make_float4(0.f, 0.f, 0.f, 0.f);
    float4 at = make_float4(0.f, 0.f, 0.f, 0.f);
#pragma unroll
    for (int i = 0; i < kBag; ++i) {
      const int iu = __builtin_amdgcn_readlane(vidx, i);
      const float4 v = ((const float4*)(emb + (size_t)iu * kHidden))[lane];
      au.x += v.x; au.y += v.y; au.z += v.z; au.w += v.w;
    }
#pragma unroll
    for (int i = 0; i < kBag; ++i) {
      const int it2 = __builtin_amdgcn_readlane(vidx, i + kBag);
      const float4 v = ((const float4*)(emb + (size_t)it2 * kHidden))[lane];
      at.x += v.x; at.y += v.y; at.z += v.z; at.w += v.w;
    }

    au.x = clip1(au.x); au.y = clip1(au.y); au.z = clip1(au.z); au.w = clip1(au.w);
    at.x = clip1(at.x); at.y = clip1(at.y); at.z = clip1(at.z); at.w = clip1(at.w);

    float p[32];
#pragma unroll
    for (int j = 0; j < 32; ++j) {
      const float4 a = *(const float4*)&sW1[j][4 * lane];
      const float4 c = *(const float4*)&sW1[j][kHidden + 4 * lane];
      p[j] = au.x * a.x + au.y * a.y + au.z * a.z + au.w * a.w +
             at.x * c.x + at.y * c.y + at.z * c.z + at.w * c.w;
    }
    const float y1 = clip1(reduce32(p, lane) + b1r);

    if ((lane & 1) == 0) sY1[wlocal][myj] = y1;
    asm volatile("s_waitcnt lgkmcnt(0)" ::: "memory");

    const float4* y4 = (const float4*)&sY1[wlocal][0];
    float y2 = b2r;
#pragma unroll
    for (int k4 = 0; k4 < 8; ++k4) {
      const float4 y = y4[k4];
      y2 += w2r[4 * k4 + 0] * y.x + w2r[4 * k4 + 1] * y.y +
            w2r[4 * k4 + 2] * y.z + w2r[4 * k4 + 3] * y.w;
    }
    y2 = clip1(y2);

    float acc = y2 * wor;
#pragma unroll
    for (int d = 1; d < 32; d <<= 1) acc += __shfl_xor(acc, d, 64);
    if (lane == 0) out[b] = acc + outb;
  }
}

extern "C" void kernel_launch(void* const* d_in, const int* in_sizes, int n_in,
                              void* d_out, int out_size, void* d_ws, size_t ws_size,
                              hipStream_t stream) {
  const int* idx_us  = (const int*)d_in[0];
  const int* idx_th  = (const int*)d_in[1];
  const float* emb   = (const float*)d_in[2];
  const float* w1    = (const float*)d_in[3];
  const float* b1    = (const float*)d_in[4];
  const float* w2    = (const float*)d_in[5];
  const float* b2    = (const float*)d_in[6];
  const float* wo    = (const float*)d_in[7];
  const float* bo    = (const float*)d_in[8];
  float* out         = (float*)d_out;

  if (ws_size >= kEmbsBytes + kXBytes) {
    __half* embs = (__half*)d_ws;
    __half* x    = (__half*)((char*)d_ws + kEmbsBytes);
    cvt_sliced<<<2560, 256, 0, stream>>>(emb, (uint4*)embs);
    nnue_gather<<<kGBlocks, kGTpb, 0, stream>>>(idx_us, idx_th, embs, x);
    nnue_mlp<<<kMBlocks, kMTpb, 0, stream>>>(x, w1, b1, w2, b2, wo, bo, out);
  } else if (ws_size >= kEmbsBytes) {
    __half* embh = (__half*)d_ws;
    cvt_emb<<<2048, 256, 0, stream>>>((const float4*)emb, (uint2*)embh);
    nnue_fwd_h<<<kBlocksH, kTpb, 0, stream>>>(idx_us, idx_th, embh, w1, b1, w2,
                                              b2, wo, bo, out);
  } else {
    nnue_fwd_f32<<<kBlocksF, kTpbF, 0, stream>>>(idx_us, idx_th, emb, w1, b1,
                                                 w2, b2, wo, bo, out);
  }
}